// Round 15
// baseline (1005.360 us; speedup 1.0000x reference)
//
#include <hip/hip_runtime.h>

#define NPTS 16384
#define KNN 16
#define HID 64
#define NCLS 10

#define GRID 32
#define GRID3 (GRID * GRID * GRID)
#define GLO -4.2f
#define GH 0.2625f
#define INVH (1.0f / GH)
#define SCAP 128   // per-query survivor capacity (LDS list)

// dist chain (3 fmaf): m2 form holds (-2x,-2y,-2z,|p|^2); query supplies raw
// (x,y,z). d = |p|^2 - 2 p.q (sq_q dropped: rank-invariant). Identical chain
// everywhere so τ comparisons are bit-exact across phases.
__device__ __forceinline__ float distm2(float qx, float qy, float qz, float4 c) {
    return fmaf(qx, c.x, fmaf(qy, c.y, fmaf(qz, c.z, c.w)));
}

// monotone float->u32, packed with orig index: u64 order == (d asc, j asc)
__device__ __forceinline__ unsigned long long dkey(float v, int j) {
    unsigned u = __float_as_uint(v);
    u = (u & 0x80000000u) ? ~u : (u | 0x80000000u);
    return ((unsigned long long)u << 32) | (unsigned)j;
}

__device__ __forceinline__ unsigned long long shfl_xor_u64(unsigned long long x, int m) {
    unsigned hi = (unsigned)__shfl_xor((int)(x >> 32), m, 64);
    unsigned lo = (unsigned)__shfl_xor((int)(x & 0xffffffffu), m, 64);
    return ((unsigned long long)hi << 32) | lo;
}

// exact wave-wide top-16 over all N (slow fallback path only)
__device__ void wave_brute16(float qx, float qy, float qz, float tqq,
                             const float4* __restrict__ spm2,
                             const int* __restrict__ sid,
                             int lane, int qorig, int* __restrict__ idx) {
    unsigned long long key[16];
#pragma unroll
    for (int u = 0; u < 16; ++u) key[u] = ~0ull;
    for (int j = lane; j < NPTS; j += 64) {
        float v = distm2(qx, qy, qz, spm2[j]);
        unsigned long long k = dkey(v, sid[j]);
        if (v <= tqq && k < key[15]) {
#pragma unroll
            for (int s = 0; s < 16; ++s) {
                unsigned long long a = k < key[s] ? k : key[s];
                unsigned long long b = k < key[s] ? key[s] : k;
                key[s] = a;
                k = b;
            }
        }
    }
    int outj = 0x7fffffff;
    for (int r = 0; r < 16; ++r) {
        unsigned long long gm = key[0];
#pragma unroll
        for (int s = 1; s < 16; ++s) gm = key[s] < gm ? key[s] : gm;
#pragma unroll
        for (int st = 1; st < 64; st <<= 1) {
            unsigned long long o = shfl_xor_u64(gm, st);
            gm = o < gm ? o : gm;
        }
        if (lane == r) outj = (int)(gm & 0xffffffffu);
#pragma unroll
        for (int s = 0; s < 16; ++s)
            if (key[s] == gm) key[s] = ~0ull;
    }
    if (lane < 16) idx[qorig * KNN + lane] = outj;
}

__device__ __forceinline__ int cellof(float x) {
    int c = (int)floorf((x - GLO) * INVH);
    return min(max(c, 0), GRID - 1);
}

// pos (N,3) -> pos4/pm2; cell id + histogram
__global__ void prep_kernel(const float* __restrict__ pos, float4* __restrict__ pos4,
                            float4* __restrict__ pm2, int* __restrict__ cellid,
                            int* __restrict__ hist) {
    int i = blockIdx.x * 256 + threadIdx.x;
    if (i < NPTS) {
        float x = pos[3 * i], y = pos[3 * i + 1], z = pos[3 * i + 2];
        float sq = fmaf(x, x, fmaf(y, y, z * z));
        pos4[i] = make_float4(x, y, z, sq);
        pm2[i] = make_float4(-2.f * x, -2.f * y, -2.f * z, sq);
        int c = (cellof(z) * GRID + cellof(y)) * GRID + cellof(x);
        cellid[i] = c;
        atomicAdd(&hist[c], 1);
    }
}

// single-block Hillis-Steele scan of the 32768-cell histogram
__global__ __launch_bounds__(1024) void scan_kernel(const int* __restrict__ hist,
                                                    int* __restrict__ cellstart,
                                                    int* __restrict__ cursor) {
    __shared__ int s[1024];
    int t = threadIdx.x;
    int base = 0;
    for (int c = 0; c < GRID3; c += 1024) {
        int v = hist[c + t];
        s[t] = v;
        __syncthreads();
        for (int off = 1; off < 1024; off <<= 1) {
            int x = (t >= off) ? s[t - off] : 0;
            __syncthreads();
            s[t] += x;
            __syncthreads();
        }
        int excl = base + s[t] - v;
        cellstart[c + t] = excl;
        cursor[c + t] = excl;
        int tot = s[1023];
        __syncthreads();
        base += tot;
    }
    if (t == 0) cellstart[GRID3] = base;
}

// scatter points into cell-sorted order (keep raw + m2 + orig id)
__global__ void scatter_kernel(const float4* __restrict__ pos4, const float4* __restrict__ pm2,
                               const int* __restrict__ cellid, int* __restrict__ cursor,
                               float4* __restrict__ ssp4, float4* __restrict__ spm2,
                               int* __restrict__ sid) {
    int i = blockIdx.x * 256 + threadIdx.x;
    if (i < NPTS) {
        int dst = atomicAdd(&cursor[cellid[i]], 1);
        ssp4[dst] = pos4[i];
        spm2[dst] = pm2[i];
        sid[dst] = i;
    }
}

// SPATIAL kNN: block = 4 independent waves x 4 consecutive sorted queries.
// Per query: tau from own +-1 cell box (stream-minima bound, >=64 pts, cap 256);
// collect pass streams x-trimmed rows of cells intersecting ball(qbbox, rmax);
// LDS rank-select. Fallback (tau=INF or overflow): exact wave brute top-16.
__global__ __launch_bounds__(256) void knn_kernel(const float4* __restrict__ ssp4,
                                                  const float4* __restrict__ spm2,
                                                  const int* __restrict__ sid,
                                                  const int* __restrict__ cellstart,
                                                  int* __restrict__ idx) {
    __shared__ unsigned long long keys[16][SCAP];   // 16KB
    __shared__ int knt[16];
    int tid = threadIdx.x;
    int lane = tid & 63;
    int w = tid >> 6;
    int sq0 = blockIdx.x * 16 + w * 4;
    float qx[4], qy[4], qz[4];
    int qorig[4];
#pragma unroll
    for (int i = 0; i < 4; ++i) {
        float4 t = ssp4[sq0 + i];       // wave-uniform scalar load
        qx[i] = t.x; qy[i] = t.y; qz[i] = t.z;
        qorig[i] = sid[sq0 + i];
    }

    // ---- Phase 1: per-query tau from local box ----
    float tq[4];
#pragma unroll
    for (int i = 0; i < 4; ++i) {
        int cx = cellof(qx[i]), cy = cellof(qy[i]), cz = cellof(qz[i]);
        int x0 = max(cx - 1, 0), x1 = min(cx + 1, GRID - 1);
        int y0 = max(cy - 1, 0), y1 = min(cy + 1, GRID - 1);
        int z0 = max(cz - 1, 0), z1 = min(cz + 1, GRID - 1);
        int cnt = 0;
        for (int span = 1; span <= 6; ++span) {
            cnt = 0;
            for (int zz = z0; zz <= z1; ++zz)
                for (int yy = y0; yy <= y1; ++yy) {
                    int rb = (zz * GRID + yy) * GRID;
                    cnt += cellstart[rb + x1 + 1] - cellstart[rb + x0];
                }
            if (cnt >= 64) break;
            x0 = max(x0 - 1, 0); x1 = min(x1 + 1, GRID - 1);
            y0 = max(y0 - 1, 0); y1 = min(y1 + 1, GRID - 1);
            z0 = max(z0 - 1, 0); z1 = min(z1 + 1, GRID - 1);
        }
        if (cnt < 64) { tq[i] = INFINITY; continue; }
        float mnl = INFINITY;
        int rem = 256;   // cap streamed points; any subset still bounds d16
        for (int zz = z0; zz <= z1 && rem > 0; ++zz)
            for (int yy = y0; yy <= y1 && rem > 0; ++yy) {
                int rb = (zz * GRID + yy) * GRID;
                int rs = cellstart[rb + x0], re = cellstart[rb + x1 + 1];
                for (int ch = rs; ch < re && rem > 0; ch += 64, rem -= 64) {
                    int j = ch + lane;
                    if (j < re) mnl = fminf(mnl, distm2(qx[i], qy[i], qz[i], spm2[j]));
                }
            }
        // stream minima (stream = lane mod 16) -> tau = max of 16 stream minima
        float m = mnl;
        m = fminf(m, __shfl_xor(m, 16, 64));
        m = fminf(m, __shfl_xor(m, 32, 64));
        m = fmaxf(m, __shfl_xor(m, 1, 64));
        m = fmaxf(m, __shfl_xor(m, 2, 64));
        m = fmaxf(m, __shfl_xor(m, 4, 64));
        m = fmaxf(m, __shfl_xor(m, 8, 64));
        tq[i] = m;   // INF only if a stream class saw no point (-> fallback)
    }

    // ---- Phase 2: collect survivors from ball-intersecting cells ----
    if (lane < 4) knt[w * 4 + lane] = 0;   // wave-private; same-wave LDS order
    float rmax2 = fmaxf(fmaxf(tq[0], tq[1]), fmaxf(tq[2], tq[3]));
    // distances here are "d = sq_p - 2 q.p"; true squared dist = d + sq_q.
    // radius^2 for query i = tq[i] + sq_q_i >= 0. Use wave-max.
    float sqq[4];
#pragma unroll
    for (int i = 0; i < 4; ++i) sqq[i] = fmaf(qx[i], qx[i], fmaf(qy[i], qy[i], qz[i] * qz[i]));
    float r2t = fmaxf(fmaxf(tq[0] + sqq[0], tq[1] + sqq[1]),
                      fmaxf(tq[2] + sqq[2], tq[3] + sqq[3]));
    bool wavebrute = (rmax2 > 1e37f) || !(r2t >= 0.f);
    if (!wavebrute) {
        float r = sqrtf(fmaxf(r2t, 0.f));
        r = fminf(r, 20.f);
        float qminx = fminf(fminf(qx[0], qx[1]), fminf(qx[2], qx[3]));
        float qmaxx = fmaxf(fmaxf(qx[0], qx[1]), fmaxf(qx[2], qx[3]));
        float qminy = fminf(fminf(qy[0], qy[1]), fminf(qy[2], qy[3]));
        float qmaxy = fmaxf(fmaxf(qy[0], qy[1]), fmaxf(qy[2], qy[3]));
        float qminz = fminf(fminf(qz[0], qz[1]), fminf(qz[2], qz[3]));
        float qmaxz = fmaxf(fmaxf(qz[0], qz[1]), fmaxf(qz[2], qz[3]));
        int bz0 = cellof(qminz - r), bz1 = cellof(qmaxz + r);
        int by0 = cellof(qminy - r), by1 = cellof(qmaxy + r);
        float r2 = r * r;
        for (int zz = bz0; zz <= bz1; ++zz) {
            float zlo = GLO + zz * GH, zhi = zlo + GH;
            float dz = fmaxf(0.f, fmaxf(zlo - qmaxz, qminz - zhi));
            // edge cells hold clamped outliers: their true coord is beyond the
            // slab, i.e. farther -> slab distance is an underestimate -> safe.
            if (zz == 0) dz = (qminz > zhi) ? dz : 0.f;           // conservative
            if (zz == GRID - 1) dz = (qmaxz < zlo) ? dz : 0.f;
            for (int yy = by0; yy <= by1; ++yy) {
                float ylo = GLO + yy * GH, yhi = ylo + GH;
                float dy = fmaxf(0.f, fmaxf(ylo - qmaxy, qminy - yhi));
                if (yy == 0) dy = (qminy > yhi) ? dy : 0.f;
                if (yy == GRID - 1) dy = (qmaxy < ylo) ? dy : 0.f;
                float d2 = dz * dz + dy * dy;
                if (d2 > r2) continue;
                float xr = sqrtf(r2 - d2);
                int xlo = cellof(qminx - xr);
                int xhi = cellof(qmaxx + xr);
                int rb = (zz * GRID + yy) * GRID;
                int rs = cellstart[rb + xlo], re = cellstart[rb + xhi + 1];
                for (int ch = rs; ch < re; ch += 64) {
                    int j = ch + lane;
                    if (j < re) {
                        float4 c = spm2[j];
                        int oid = sid[j];
                        float v0 = distm2(qx[0], qy[0], qz[0], c);
                        float v1 = distm2(qx[1], qy[1], qz[1], c);
                        float v2 = distm2(qx[2], qy[2], qz[2], c);
                        float v3 = distm2(qx[3], qy[3], qz[3], c);
                        if (v0 <= tq[0]) { int s = atomicAdd(&knt[w * 4 + 0], 1); if (s < SCAP) keys[w * 4 + 0][s] = dkey(v0, oid); }
                        if (v1 <= tq[1]) { int s = atomicAdd(&knt[w * 4 + 1], 1); if (s < SCAP) keys[w * 4 + 1][s] = dkey(v1, oid); }
                        if (v2 <= tq[2]) { int s = atomicAdd(&knt[w * 4 + 2], 1); if (s < SCAP) keys[w * 4 + 2][s] = dkey(v2, oid); }
                        if (v3 <= tq[3]) { int s = atomicAdd(&knt[w * 4 + 3], 1); if (s < SCAP) keys[w * 4 + 3][s] = dkey(v3, oid); }
                    }
                }
            }
        }
    }

    // ---- Extraction: rank-select per query; fallback = exact brute ----
#pragma unroll
    for (int e = 0; e < 4; ++e) {
        int li = w * 4 + e;
        int ntot = knt[li];
        if (wavebrute || tq[e] > 1e37f || ntot > SCAP || ntot < KNN) {
            wave_brute16(qx[e], qy[e], qz[e], INFINITY, spm2, sid, lane, qorig[e], idx);
            continue;
        }
        unsigned long long k0 = (lane < ntot) ? keys[li][lane] : ~0ull;
        unsigned long long k1 = (lane + 64 < ntot) ? keys[li][lane + 64] : ~0ull;
        int r0 = 0, r1 = 0;
        for (int t = 0; t < ntot; ++t) {
            unsigned long long k = keys[li][t];   // broadcast ds_read
            r0 += (int)(k < k0);
            r1 += (int)(k < k1);
        }
        if (lane < ntot && r0 < KNN) idx[qorig[e] * KNN + r0] = (int)(k0 & 0xffffffffu);
        if (lane + 64 < ntot && r1 < KNN) idx[qorig[e] * KNN + r1] = (int)(k1 & 0xffffffffu);
    }
}

// FUSED EdgeConv1 + ec2_pre (h1 never touches global) — unchanged from R14.
__global__ __launch_bounds__(256) void ec12_kernel(const float4* __restrict__ pos4,
                                                   const int* __restrict__ idx,
                                                   const float* __restrict__ W1,
                                                   const float* __restrict__ b1,
                                                   const float* __restrict__ W2,
                                                   const float* __restrict__ b2,
                                                   float* __restrict__ C2,
                                                   float* __restrict__ Y2) {
    __shared__ float h1s[16][64];
    int t = threadIdx.x & 63;
    int w = threadIdx.x >> 6;
    int pb = blockIdx.x * 16 + w * 4;
    float w0 = W1[0 * HID + t], w1 = W1[1 * HID + t], w2 = W1[2 * HID + t];
    float v0 = W1[3 * HID + t], v1 = W1[4 * HID + t], v2 = W1[5 * HID + t];
    float bt1 = b1[t];
#pragma unroll
    for (int i = 0; i < 4; ++i) {
        int p = pb + i;
        float4 xi = pos4[p];
        float C = bt1 + xi.x * (w0 - v0) + xi.y * (w1 - v1) + xi.z * (w2 - v2);
        float m = -INFINITY;
#pragma unroll
        for (int k = 0; k < KNN; ++k) {
            int j = idx[p * KNN + k];
            float4 xj = pos4[j];
            m = fmaxf(m, fmaf(xj.x, v0, fmaf(xj.y, v1, xj.z * v2)));
        }
        h1s[w * 4 + i][t] = fmaxf(C + m, 0.f);
    }
    __syncthreads();
    float aa[4] = {0.f, 0.f, 0.f, 0.f};
    float ab[4] = {0.f, 0.f, 0.f, 0.f};
#pragma unroll 8
    for (int f = 0; f < 64; ++f) {
        float wa = W2[f * HID + t];
        float wb = W2[(64 + f) * HID + t];
#pragma unroll
        for (int i = 0; i < 4; ++i) {
            float h = h1s[w * 4 + i][f];
            aa[i] = fmaf(h, wa, aa[i]);
            ab[i] = fmaf(h, wb, ab[i]);
        }
    }
    float bt = b2[t];
#pragma unroll
    for (int i = 0; i < 4; ++i) {
        C2[(pb + i) * HID + t] = bt + aa[i] - ab[i];
        Y2[(pb + i) * HID + t] = ab[i];
    }
}

__global__ __launch_bounds__(256) void ec2_maxpool_kernel(const float* __restrict__ C2,
                                                          const float* __restrict__ Y2,
                                                          const int* __restrict__ idx,
                                                          float* __restrict__ gpartial) {
    int t = threadIdx.x & 63;
    int lp = threadIdx.x >> 6;
    int p = blockIdx.x * 4 + lp;
    float m = -INFINITY;
#pragma unroll
    for (int k = 0; k < KNN; ++k) {
        int j = idx[p * KNN + k];
        m = fmaxf(m, Y2[j * HID + t]);
    }
    float val = fmaxf(C2[p * HID + t] + m, 0.f);
    __shared__ float red[4][64];
    red[lp][t] = val;
    __syncthreads();
    if (lp == 0) {
        float g = fmaxf(fmaxf(red[0][t], red[1][t]), fmaxf(red[2][t], red[3][t]));
        gpartial[blockIdx.x * 64 + t] = g;
    }
}

__global__ __launch_bounds__(256) void greduce2_kernel(const float* __restrict__ gpartial,
                                                       float* __restrict__ gp2) {
    __shared__ float red[4][64];
    int f = threadIdx.x & 63;
    int w = threadIdx.x >> 6;
    int r0 = blockIdx.x * 16 + w * 4;
    float m = -INFINITY;
#pragma unroll
    for (int r = 0; r < 4; ++r) m = fmaxf(m, gpartial[(r0 + r) * 64 + f]);
    red[w][f] = m;
    __syncthreads();
    if (w == 0)
        gp2[blockIdx.x * 64 + f] =
            fmaxf(fmaxf(red[0][f], red[1][f]), fmaxf(red[2][f], red[3][f]));
}

__global__ __launch_bounds__(256) void tail2_kernel(const float* __restrict__ gp2,
                                                    const float* __restrict__ Wc,
                                                    const float* __restrict__ bc,
                                                    float* __restrict__ out) {
    __shared__ float red[4][64];
    __shared__ float g[64];
    int f = threadIdx.x & 63;
    int w = threadIdx.x >> 6;
    float m = -INFINITY;
    for (int i = w; i < 256; i += 4) m = fmaxf(m, gp2[i * 64 + f]);
    red[w][f] = m;
    __syncthreads();
    if (w == 0) g[f] = fmaxf(fmaxf(red[0][f], red[1][f]), fmaxf(red[2][f], red[3][f]));
    __syncthreads();
    if (threadIdx.x < NCLS) {
        float a = bc[threadIdx.x];
#pragma unroll
        for (int h = 0; h < HID; ++h) a = fmaf(g[h], Wc[h * NCLS + threadIdx.x], a);
        out[threadIdx.x] = a;
    }
}

extern "C" void kernel_launch(void* const* d_in, const int* in_sizes, int n_in,
                              void* d_out, int out_size, void* d_ws, size_t ws_size,
                              hipStream_t stream) {
    const float* pos = (const float*)d_in[0];
    // d_in[1] = batch (all zeros, num_segments=1) -> unused
    const float* W1 = (const float*)d_in[2];
    const float* b1 = (const float*)d_in[3];
    const float* W2 = (const float*)d_in[4];
    const float* b2 = (const float*)d_in[5];
    const float* Wc = (const float*)d_in[6];
    const float* bc = (const float*)d_in[7];
    float* out = (float*)d_out;

    char* ws = (char*)d_ws;
    size_t o = 0;
    auto alloc = [&](size_t bytes) { size_t r = o; o += (bytes + 255) & ~size_t(255); return r; };
    size_t fm = (size_t)NPTS * HID * 4;
    size_t o_pos4 = alloc((size_t)NPTS * 16);
    size_t o_pm2 = alloc((size_t)NPTS * 16);
    size_t o_ssp4 = alloc((size_t)NPTS * 16);
    size_t o_spm2 = alloc((size_t)NPTS * 16);
    size_t o_cellid = alloc((size_t)NPTS * 4);
    size_t o_sid = alloc((size_t)NPTS * 4);
    size_t o_hist = alloc((size_t)GRID3 * 4);
    size_t o_cstart = alloc((size_t)(GRID3 + 1) * 4);
    size_t o_cursor = alloc((size_t)GRID3 * 4);
    size_t o_idx = alloc((size_t)NPTS * KNN * 4);
    size_t o_C2 = alloc(fm);
    size_t o_Y2 = alloc(fm);
    size_t o_gp = alloc((size_t)(NPTS / 4) * HID * 4);
    size_t o_gp2 = alloc((size_t)256 * HID * 4);

    float4* pos4 = (float4*)(ws + o_pos4);
    float4* pm2 = (float4*)(ws + o_pm2);
    float4* ssp4 = (float4*)(ws + o_ssp4);
    float4* spm2 = (float4*)(ws + o_spm2);
    int* cellid = (int*)(ws + o_cellid);
    int* sid = (int*)(ws + o_sid);
    int* hist = (int*)(ws + o_hist);
    int* cstart = (int*)(ws + o_cstart);
    int* cursor = (int*)(ws + o_cursor);
    int* idx = (int*)(ws + o_idx);
    float* C2 = (float*)(ws + o_C2);
    float* Y2 = (float*)(ws + o_Y2);
    float* gp = (float*)(ws + o_gp);
    float* gp2 = (float*)(ws + o_gp2);

    hipMemsetAsync(hist, 0, (size_t)GRID3 * 4, stream);

    prep_kernel<<<NPTS / 256, 256, 0, stream>>>(pos, pos4, pm2, cellid, hist);
    scan_kernel<<<1, 1024, 0, stream>>>(hist, cstart, cursor);
    scatter_kernel<<<NPTS / 256, 256, 0, stream>>>(pos4, pm2, cellid, cursor, ssp4, spm2, sid);
    knn_kernel<<<NPTS / 16, 256, 0, stream>>>(ssp4, spm2, sid, cstart, idx);
    ec12_kernel<<<NPTS / 16, 256, 0, stream>>>(pos4, idx, W1, b1, W2, b2, C2, Y2);
    ec2_maxpool_kernel<<<NPTS / 4, 256, 0, stream>>>(C2, Y2, idx, gp);
    greduce2_kernel<<<256, 256, 0, stream>>>(gp, gp2);
    tail2_kernel<<<1, 256, 0, stream>>>(gp2, Wc, bc, out);
}

// Round 16
// 799.740 us; speedup vs baseline: 1.2571x; 1.2571x over previous
//
#include <hip/hip_runtime.h>

#define NPTS 16384
#define KNN 16
#define HID 64
#define NCLS 10

#define GRID 32
#define GRID3 (GRID * GRID * GRID)
#define GLO -4.2f
#define GH 0.2625f
#define INVH (1.0f / GH)
#define SCAP 128   // per-query survivor capacity (LDS list)

// dist chain (3 fmaf): m2 form holds (-2x,-2y,-2z,|p|^2); query supplies raw
// (x,y,z). d = |p|^2 - 2 p.q (sq_q dropped: rank-invariant). Identical chain
// everywhere so τ comparisons are bit-exact across phases.
__device__ __forceinline__ float distm2(float qx, float qy, float qz, float4 c) {
    return fmaf(qx, c.x, fmaf(qy, c.y, fmaf(qz, c.z, c.w)));
}

// monotone float->u32, packed with orig index: u64 order == (d asc, j asc)
__device__ __forceinline__ unsigned long long dkey(float v, int j) {
    unsigned u = __float_as_uint(v);
    u = (u & 0x80000000u) ? ~u : (u | 0x80000000u);
    return ((unsigned long long)u << 32) | (unsigned)j;
}

__device__ __forceinline__ unsigned long long shfl_xor_u64(unsigned long long x, int m) {
    unsigned hi = (unsigned)__shfl_xor((int)(x >> 32), m, 64);
    unsigned lo = (unsigned)__shfl_xor((int)(x & 0xffffffffu), m, 64);
    return ((unsigned long long)hi << 32) | lo;
}

__device__ __forceinline__ int lane_prefix(unsigned long long mask) {
    int p = __builtin_amdgcn_mbcnt_lo((unsigned)mask, 0);
    return __builtin_amdgcn_mbcnt_hi((unsigned)(mask >> 32), p);
}

// TWO-PASS exact wave brute (fallback): pass1 computes own stream-tau
// (finite!), pass2 does tau-filtered insert (rare bodies). ~10k inst.
__device__ void wave_brute2p(float qx, float qy, float qz,
                             const float4* __restrict__ spm2,
                             const int* __restrict__ sid,
                             int lane, int qorig, int* __restrict__ idx) {
    float mn = INFINITY;
    for (int j = lane; j < NPTS; j += 64) mn = fminf(mn, distm2(qx, qy, qz, spm2[j]));
    float m = mn;
    m = fminf(m, __shfl_xor(m, 16, 64));
    m = fminf(m, __shfl_xor(m, 32, 64));
    m = fmaxf(m, __shfl_xor(m, 1, 64));
    m = fmaxf(m, __shfl_xor(m, 2, 64));
    m = fmaxf(m, __shfl_xor(m, 4, 64));
    m = fmaxf(m, __shfl_xor(m, 8, 64));
    float tq = m;   // streams = lane mod 16 all non-empty (256 pts/lane)
    unsigned long long key[16];
#pragma unroll
    for (int u = 0; u < 16; ++u) key[u] = ~0ull;
    for (int j = lane; j < NPTS; j += 64) {
        float v = distm2(qx, qy, qz, spm2[j]);
        if (v <= tq) {
            unsigned long long k = dkey(v, sid[j]);
            if (k < key[15]) {
#pragma unroll
                for (int s = 0; s < 16; ++s) {
                    unsigned long long a = k < key[s] ? k : key[s];
                    unsigned long long b = k < key[s] ? key[s] : k;
                    key[s] = a;
                    k = b;
                }
            }
        }
    }
    int outj = 0x7fffffff;
    for (int r = 0; r < 16; ++r) {
        unsigned long long gm = key[0];
#pragma unroll
        for (int s = 1; s < 16; ++s) gm = key[s] < gm ? key[s] : gm;
#pragma unroll
        for (int st = 1; st < 64; st <<= 1) {
            unsigned long long o = shfl_xor_u64(gm, st);
            gm = o < gm ? o : gm;
        }
        if (lane == r) outj = (int)(gm & 0xffffffffu);
#pragma unroll
        for (int s = 0; s < 16; ++s)
            if (key[s] == gm) key[s] = ~0ull;
    }
    if (lane < 16) idx[qorig * KNN + lane] = outj;
}

__device__ __forceinline__ int cellof(float x) {
    int c = (int)floorf((x - GLO) * INVH);
    return min(max(c, 0), GRID - 1);
}

// pos (N,3) -> pos4/pm2; cell id + histogram
__global__ void prep_kernel(const float* __restrict__ pos, float4* __restrict__ pos4,
                            float4* __restrict__ pm2, int* __restrict__ cellid,
                            int* __restrict__ hist) {
    int i = blockIdx.x * 256 + threadIdx.x;
    if (i < NPTS) {
        float x = pos[3 * i], y = pos[3 * i + 1], z = pos[3 * i + 2];
        float sq = fmaf(x, x, fmaf(y, y, z * z));
        pos4[i] = make_float4(x, y, z, sq);
        pm2[i] = make_float4(-2.f * x, -2.f * y, -2.f * z, sq);
        int c = (cellof(z) * GRID + cellof(y)) * GRID + cellof(x);
        cellid[i] = c;
        atomicAdd(&hist[c], 1);
    }
}

// single-block Hillis-Steele scan of the 32768-cell histogram
__global__ __launch_bounds__(1024) void scan_kernel(const int* __restrict__ hist,
                                                    int* __restrict__ cellstart,
                                                    int* __restrict__ cursor) {
    __shared__ int s[1024];
    int t = threadIdx.x;
    int base = 0;
    for (int c = 0; c < GRID3; c += 1024) {
        int v = hist[c + t];
        s[t] = v;
        __syncthreads();
        for (int off = 1; off < 1024; off <<= 1) {
            int x = (t >= off) ? s[t - off] : 0;
            __syncthreads();
            s[t] += x;
            __syncthreads();
        }
        int excl = base + s[t] - v;
        cellstart[c + t] = excl;
        cursor[c + t] = excl;
        int tot = s[1023];
        __syncthreads();
        base += tot;
    }
    if (t == 0) cellstart[GRID3] = base;
}

// scatter points into cell-sorted order (keep raw + m2 + orig id)
__global__ void scatter_kernel(const float4* __restrict__ pos4, const float4* __restrict__ pm2,
                               const int* __restrict__ cellid, int* __restrict__ cursor,
                               float4* __restrict__ ssp4, float4* __restrict__ spm2,
                               int* __restrict__ sid) {
    int i = blockIdx.x * 256 + threadIdx.x;
    if (i < NPTS) {
        int dst = atomicAdd(&cursor[cellid[i]], 1);
        ssp4[dst] = pos4[i];
        spm2[dst] = pm2[i];
        sid[dst] = i;
    }
}

// SPATIAL kNN v2: block = 4 independent waves x 4 consecutive sorted queries.
// tau: FULL +-span box streamed (unbiased, expand until >=64 pts). Collect:
// ballot-compacted pushes (no LDS atomics, wave-uniform reg counters, no
// barriers anywhere). Fallback per query: two-pass brute with finite tau.
__global__ __launch_bounds__(256) void knn_kernel(const float4* __restrict__ ssp4,
                                                  const float4* __restrict__ spm2,
                                                  const int* __restrict__ sid,
                                                  const int* __restrict__ cellstart,
                                                  int* __restrict__ idx) {
    __shared__ unsigned long long keys[16][SCAP];   // 16KB, wave-private slices
    int tid = threadIdx.x;
    int lane = tid & 63;
    int w = tid >> 6;
    int li0 = w * 4;
    int sq0 = blockIdx.x * 16 + w * 4;
    float qx[4], qy[4], qz[4];
    int qorig[4];
#pragma unroll
    for (int i = 0; i < 4; ++i) {
        float4 t = ssp4[sq0 + i];       // wave-uniform scalar load
        qx[i] = t.x; qy[i] = t.y; qz[i] = t.z;
        qorig[i] = sid[sq0 + i];
    }

    // ---- Phase 1: per-query tau from FULL expanded box (unbiased) ----
    float tq[4];
    bool valid[4];
#pragma unroll
    for (int i = 0; i < 4; ++i) {
        int cx = cellof(qx[i]), cy = cellof(qy[i]), cz = cellof(qz[i]);
        int x0 = max(cx - 1, 0), x1 = min(cx + 1, GRID - 1);
        int y0 = max(cy - 1, 0), y1 = min(cy + 1, GRID - 1);
        int z0 = max(cz - 1, 0), z1 = min(cz + 1, GRID - 1);
        int cnt = 0;
        for (int span = 0; span < GRID; ++span) {
            cnt = 0;
            for (int zz = z0; zz <= z1; ++zz)
                for (int yy = y0; yy <= y1; ++yy) {
                    int rb = (zz * GRID + yy) * GRID;
                    cnt += cellstart[rb + x1 + 1] - cellstart[rb + x0];
                }
            if (cnt >= 64) break;
            x0 = max(x0 - 1, 0); x1 = min(x1 + 1, GRID - 1);
            y0 = max(y0 - 1, 0); y1 = min(y1 + 1, GRID - 1);
            z0 = max(z0 - 1, 0); z1 = min(z1 + 1, GRID - 1);
        }
        // stream the WHOLE box (no biased cap)
        float mnl = INFINITY;
        for (int zz = z0; zz <= z1; ++zz)
            for (int yy = y0; yy <= y1; ++yy) {
                int rb = (zz * GRID + yy) * GRID;
                int rs = cellstart[rb + x0], re = cellstart[rb + x1 + 1];
                for (int ch = rs; ch < re; ch += 64) {
                    int j = ch + lane;
                    if (j < re) mnl = fminf(mnl, distm2(qx[i], qy[i], qz[i], spm2[j]));
                }
            }
        float m = mnl;
        m = fminf(m, __shfl_xor(m, 16, 64));
        m = fminf(m, __shfl_xor(m, 32, 64));
        m = fmaxf(m, __shfl_xor(m, 1, 64));
        m = fmaxf(m, __shfl_xor(m, 2, 64));
        m = fmaxf(m, __shfl_xor(m, 4, 64));
        m = fmaxf(m, __shfl_xor(m, 8, 64));
        tq[i] = m;                       // INF only if some lane-stream empty
        valid[i] = isfinite(m);
    }
    float tqc[4];
#pragma unroll
    for (int i = 0; i < 4; ++i) tqc[i] = valid[i] ? tq[i] : -INFINITY;

    // ---- Phase 2: ballot-compacted collect over ball-intersecting cells ----
    int kcnt[4] = {0, 0, 0, 0};
    float sqq[4];
#pragma unroll
    for (int i = 0; i < 4; ++i) sqq[i] = fmaf(qx[i], qx[i], fmaf(qy[i], qy[i], qz[i] * qz[i]));
    float r2t = -1.f;
#pragma unroll
    for (int i = 0; i < 4; ++i)
        if (valid[i]) r2t = fmaxf(r2t, tq[i] + sqq[i]);
    float qminx = fminf(fminf(qx[0], qx[1]), fminf(qx[2], qx[3]));
    float qmaxx = fmaxf(fmaxf(qx[0], qx[1]), fmaxf(qx[2], qx[3]));
    float qminy = fminf(fminf(qy[0], qy[1]), fminf(qy[2], qy[3]));
    float qmaxy = fmaxf(fmaxf(qy[0], qy[1]), fmaxf(qy[2], qy[3]));
    float qminz = fminf(fminf(qz[0], qz[1]), fminf(qz[2], qz[3]));
    float qmaxz = fmaxf(fmaxf(qz[0], qz[1]), fmaxf(qz[2], qz[3]));
    // pathological sorted-window (x-row wrap) -> skip collect, brute fallback
    bool doCollect = (r2t >= 0.f) && ((qmaxx - qminx) < 1.5f);
    if (doCollect) {
        float r = sqrtf(fmaxf(r2t, 0.f)) * 1.0001f + 1e-6f;   // ulp guard
        float r2 = r * r;
        int bz0 = cellof(qminz - r), bz1 = cellof(qmaxz + r);
        int by0 = cellof(qminy - r), by1 = cellof(qmaxy + r);
        for (int zz = bz0; zz <= bz1; ++zz) {
            float zlo = GLO + zz * GH, zhi = zlo + GH;
            // edge cells hold clamped points extending to +-inf: drop that side
            float dz = fmaxf(0.f, fmaxf((zz == 0) ? 0.f : zlo - qmaxz,
                                        (zz == GRID - 1) ? 0.f : qminz - zhi));
            for (int yy = by0; yy <= by1; ++yy) {
                float ylo = GLO + yy * GH, yhi = ylo + GH;
                float dy = fmaxf(0.f, fmaxf((yy == 0) ? 0.f : ylo - qmaxy,
                                            (yy == GRID - 1) ? 0.f : qminy - yhi));
                float d2 = dz * dz + dy * dy;
                if (d2 > r2) continue;
                float xr = sqrtf(r2 - d2) * 1.0001f + 1e-6f;
                int xlo = cellof(qminx - xr);
                int xhi = cellof(qmaxx + xr);
                int rb = (zz * GRID + yy) * GRID;
                int rs = cellstart[rb + xlo], re = cellstart[rb + xhi + 1];
                for (int ch = rs; ch < re; ch += 64) {
                    int j = ch + lane;
                    bool inb = j < re;
                    float4 c = inb ? spm2[j] : make_float4(0.f, 0.f, 0.f, 3e38f);
                    int oid = inb ? sid[j] : 0;
#pragma unroll
                    for (int i = 0; i < 4; ++i) {
                        float v = distm2(qx[i], qy[i], qz[i], c);
                        bool pred = v <= tqc[i];   // pad c.w=3e38 -> never passes
                        unsigned long long mask = __ballot(pred);
                        if (mask) {
                            int pfx = lane_prefix(mask);
                            if (pred) {
                                int s = kcnt[i] + pfx;
                                if (s < SCAP) keys[li0 + i][s] = dkey(v, oid);
                            }
                            kcnt[i] += (int)__popcll(mask);
                        }
                    }
                }
            }
        }
    }

    // ---- Extraction: rank-select per query; fallback = two-pass brute ----
#pragma unroll
    for (int e = 0; e < 4; ++e) {
        int ntot = kcnt[e];
        if (!doCollect || !valid[e] || ntot > SCAP || ntot < KNN) {
            wave_brute2p(qx[e], qy[e], qz[e], spm2, sid, lane, qorig[e], idx);
            continue;
        }
        unsigned long long k0 = (lane < ntot) ? keys[li0 + e][lane] : ~0ull;
        unsigned long long k1 = (lane + 64 < ntot) ? keys[li0 + e][lane + 64] : ~0ull;
        int r0 = 0, r1 = 0;
        for (int t = 0; t < ntot; ++t) {
            unsigned long long k = keys[li0 + e][t];   // broadcast ds_read
            r0 += (int)(k < k0);
            r1 += (int)(k < k1);
        }
        if (lane < ntot && r0 < KNN) idx[qorig[e] * KNN + r0] = (int)(k0 & 0xffffffffu);
        if (lane + 64 < ntot && r1 < KNN) idx[qorig[e] * KNN + r1] = (int)(k1 & 0xffffffffu);
    }
}

// FUSED EdgeConv1 + ec2_pre (h1 never touches global) — unchanged.
__global__ __launch_bounds__(256) void ec12_kernel(const float4* __restrict__ pos4,
                                                   const int* __restrict__ idx,
                                                   const float* __restrict__ W1,
                                                   const float* __restrict__ b1,
                                                   const float* __restrict__ W2,
                                                   const float* __restrict__ b2,
                                                   float* __restrict__ C2,
                                                   float* __restrict__ Y2) {
    __shared__ float h1s[16][64];
    int t = threadIdx.x & 63;
    int w = threadIdx.x >> 6;
    int pb = blockIdx.x * 16 + w * 4;
    float w0 = W1[0 * HID + t], w1 = W1[1 * HID + t], w2 = W1[2 * HID + t];
    float v0 = W1[3 * HID + t], v1 = W1[4 * HID + t], v2 = W1[5 * HID + t];
    float bt1 = b1[t];
#pragma unroll
    for (int i = 0; i < 4; ++i) {
        int p = pb + i;
        float4 xi = pos4[p];
        float C = bt1 + xi.x * (w0 - v0) + xi.y * (w1 - v1) + xi.z * (w2 - v2);
        float m = -INFINITY;
#pragma unroll
        for (int k = 0; k < KNN; ++k) {
            int j = idx[p * KNN + k];
            float4 xj = pos4[j];
            m = fmaxf(m, fmaf(xj.x, v0, fmaf(xj.y, v1, xj.z * v2)));
        }
        h1s[w * 4 + i][t] = fmaxf(C + m, 0.f);
    }
    __syncthreads();
    float aa[4] = {0.f, 0.f, 0.f, 0.f};
    float ab[4] = {0.f, 0.f, 0.f, 0.f};
#pragma unroll 8
    for (int f = 0; f < 64; ++f) {
        float wa = W2[f * HID + t];
        float wb = W2[(64 + f) * HID + t];
#pragma unroll
        for (int i = 0; i < 4; ++i) {
            float h = h1s[w * 4 + i][f];
            aa[i] = fmaf(h, wa, aa[i]);
            ab[i] = fmaf(h, wb, ab[i]);
        }
    }
    float bt = b2[t];
#pragma unroll
    for (int i = 0; i < 4; ++i) {
        C2[(pb + i) * HID + t] = bt + aa[i] - ab[i];
        Y2[(pb + i) * HID + t] = ab[i];
    }
}

__global__ __launch_bounds__(256) void ec2_maxpool_kernel(const float* __restrict__ C2,
                                                          const float* __restrict__ Y2,
                                                          const int* __restrict__ idx,
                                                          float* __restrict__ gpartial) {
    int t = threadIdx.x & 63;
    int lp = threadIdx.x >> 6;
    int p = blockIdx.x * 4 + lp;
    float m = -INFINITY;
#pragma unroll
    for (int k = 0; k < KNN; ++k) {
        int j = idx[p * KNN + k];
        m = fmaxf(m, Y2[j * HID + t]);
    }
    float val = fmaxf(C2[p * HID + t] + m, 0.f);
    __shared__ float red[4][64];
    red[lp][t] = val;
    __syncthreads();
    if (lp == 0) {
        float g = fmaxf(fmaxf(red[0][t], red[1][t]), fmaxf(red[2][t], red[3][t]));
        gpartial[blockIdx.x * 64 + t] = g;
    }
}

__global__ __launch_bounds__(256) void greduce2_kernel(const float* __restrict__ gpartial,
                                                       float* __restrict__ gp2) {
    __shared__ float red[4][64];
    int f = threadIdx.x & 63;
    int w = threadIdx.x >> 6;
    int r0 = blockIdx.x * 16 + w * 4;
    float m = -INFINITY;
#pragma unroll
    for (int r = 0; r < 4; ++r) m = fmaxf(m, gpartial[(r0 + r) * 64 + f]);
    red[w][f] = m;
    __syncthreads();
    if (w == 0)
        gp2[blockIdx.x * 64 + f] =
            fmaxf(fmaxf(red[0][f], red[1][f]), fmaxf(red[2][f], red[3][f]));
}

__global__ __launch_bounds__(256) void tail2_kernel(const float* __restrict__ gp2,
                                                    const float* __restrict__ Wc,
                                                    const float* __restrict__ bc,
                                                    float* __restrict__ out) {
    __shared__ float red[4][64];
    __shared__ float g[64];
    int f = threadIdx.x & 63;
    int w = threadIdx.x >> 6;
    float m = -INFINITY;
    for (int i = w; i < 256; i += 4) m = fmaxf(m, gp2[i * 64 + f]);
    red[w][f] = m;
    __syncthreads();
    if (w == 0) g[f] = fmaxf(fmaxf(red[0][f], red[1][f]), fmaxf(red[2][f], red[3][f]));
    __syncthreads();
    if (threadIdx.x < NCLS) {
        float a = bc[threadIdx.x];
#pragma unroll
        for (int h = 0; h < HID; ++h) a = fmaf(g[h], Wc[h * NCLS + threadIdx.x], a);
        out[threadIdx.x] = a;
    }
}

extern "C" void kernel_launch(void* const* d_in, const int* in_sizes, int n_in,
                              void* d_out, int out_size, void* d_ws, size_t ws_size,
                              hipStream_t stream) {
    const float* pos = (const float*)d_in[0];
    // d_in[1] = batch (all zeros, num_segments=1) -> unused
    const float* W1 = (const float*)d_in[2];
    const float* b1 = (const float*)d_in[3];
    const float* W2 = (const float*)d_in[4];
    const float* b2 = (const float*)d_in[5];
    const float* Wc = (const float*)d_in[6];
    const float* bc = (const float*)d_in[7];
    float* out = (float*)d_out;

    char* ws = (char*)d_ws;
    size_t o = 0;
    auto alloc = [&](size_t bytes) { size_t r = o; o += (bytes + 255) & ~size_t(255); return r; };
    size_t fm = (size_t)NPTS * HID * 4;
    size_t o_pos4 = alloc((size_t)NPTS * 16);
    size_t o_pm2 = alloc((size_t)NPTS * 16);
    size_t o_ssp4 = alloc((size_t)NPTS * 16);
    size_t o_spm2 = alloc((size_t)NPTS * 16);
    size_t o_cellid = alloc((size_t)NPTS * 4);
    size_t o_sid = alloc((size_t)NPTS * 4);
    size_t o_hist = alloc((size_t)GRID3 * 4);
    size_t o_cstart = alloc((size_t)(GRID3 + 1) * 4);
    size_t o_cursor = alloc((size_t)GRID3 * 4);
    size_t o_idx = alloc((size_t)NPTS * KNN * 4);
    size_t o_C2 = alloc(fm);
    size_t o_Y2 = alloc(fm);
    size_t o_gp = alloc((size_t)(NPTS / 4) * HID * 4);
    size_t o_gp2 = alloc((size_t)256 * HID * 4);

    float4* pos4 = (float4*)(ws + o_pos4);
    float4* pm2 = (float4*)(ws + o_pm2);
    float4* ssp4 = (float4*)(ws + o_ssp4);
    float4* spm2 = (float4*)(ws + o_spm2);
    int* cellid = (int*)(ws + o_cellid);
    int* sid = (int*)(ws + o_sid);
    int* hist = (int*)(ws + o_hist);
    int* cstart = (int*)(ws + o_cstart);
    int* cursor = (int*)(ws + o_cursor);
    int* idx = (int*)(ws + o_idx);
    float* C2 = (float*)(ws + o_C2);
    float* Y2 = (float*)(ws + o_Y2);
    float* gp = (float*)(ws + o_gp);
    float* gp2 = (float*)(ws + o_gp2);

    hipMemsetAsync(hist, 0, (size_t)GRID3 * 4, stream);

    prep_kernel<<<NPTS / 256, 256, 0, stream>>>(pos, pos4, pm2, cellid, hist);
    scan_kernel<<<1, 1024, 0, stream>>>(hist, cstart, cursor);
    scatter_kernel<<<NPTS / 256, 256, 0, stream>>>(pos4, pm2, cellid, cursor, ssp4, spm2, sid);
    knn_kernel<<<NPTS / 16, 256, 0, stream>>>(ssp4, spm2, sid, cstart, idx);
    ec12_kernel<<<NPTS / 16, 256, 0, stream>>>(pos4, idx, W1, b1, W2, b2, C2, Y2);
    ec2_maxpool_kernel<<<NPTS / 4, 256, 0, stream>>>(C2, Y2, idx, gp);
    greduce2_kernel<<<256, 256, 0, stream>>>(gp, gp2);
    tail2_kernel<<<1, 256, 0, stream>>>(gp2, Wc, bc, out);
}

// Round 17
// 639.738 us; speedup vs baseline: 1.5715x; 1.2501x over previous
//
#include <hip/hip_runtime.h>

#define NPTS 16384
#define KNN 16
#define HID 64
#define NCLS 10

#define GRID 32
#define GRID3 (GRID * GRID * GRID)
#define GLO -4.2f
#define GH 0.2625f
#define INVH (1.0f / GH)
#define SCAP 192   // per-query survivor capacity (LDS list)
#define TWIN 512   // tau sample window (sorted points)

// dist chain (3 fmaf): m2 form holds (-2x,-2y,-2z,|p|^2); query supplies raw
// (x,y,z). d = |p|^2 - 2 p.q (sq_q dropped: rank-invariant). Identical chain
// everywhere so τ comparisons are bit-exact across phases.
__device__ __forceinline__ float distm2(float qx, float qy, float qz, float4 c) {
    return fmaf(qx, c.x, fmaf(qy, c.y, fmaf(qz, c.z, c.w)));
}

// monotone float->u32, packed with orig index: u64 order == (d asc, j asc)
__device__ __forceinline__ unsigned long long dkey(float v, int j) {
    unsigned u = __float_as_uint(v);
    u = (u & 0x80000000u) ? ~u : (u | 0x80000000u);
    return ((unsigned long long)u << 32) | (unsigned)j;
}

__device__ __forceinline__ unsigned long long shfl_xor_u64(unsigned long long x, int m) {
    unsigned hi = (unsigned)__shfl_xor((int)(x >> 32), m, 64);
    unsigned lo = (unsigned)__shfl_xor((int)(x & 0xffffffffu), m, 64);
    return ((unsigned long long)hi << 32) | lo;
}

// TWO-PASS exact wave brute over ORIGINAL pm2 (fallback; finite own-tau).
__device__ void wave_brute2p(float qx, float qy, float qz,
                             const float4* __restrict__ pm2,
                             int lane, int qorig, int* __restrict__ idx) {
    float mn = INFINITY;
    for (int j = lane; j < NPTS; j += 64) mn = fminf(mn, distm2(qx, qy, qz, pm2[j]));
    float m = mn;
    m = fminf(m, __shfl_xor(m, 16, 64));
    m = fminf(m, __shfl_xor(m, 32, 64));
    m = fmaxf(m, __shfl_xor(m, 1, 64));
    m = fmaxf(m, __shfl_xor(m, 2, 64));
    m = fmaxf(m, __shfl_xor(m, 4, 64));
    m = fmaxf(m, __shfl_xor(m, 8, 64));
    float tq = m;   // streams = lane mod 16 all non-empty (256 pts/lane)
    unsigned long long key[16];
#pragma unroll
    for (int u = 0; u < 16; ++u) key[u] = ~0ull;
    for (int j = lane; j < NPTS; j += 64) {
        float v = distm2(qx, qy, qz, pm2[j]);
        if (v <= tq) {
            unsigned long long k = dkey(v, j);
            if (k < key[15]) {
#pragma unroll
                for (int s = 0; s < 16; ++s) {
                    unsigned long long a = k < key[s] ? k : key[s];
                    unsigned long long b = k < key[s] ? key[s] : k;
                    key[s] = a;
                    k = b;
                }
            }
        }
    }
    int outj = 0x7fffffff;
    for (int r = 0; r < 16; ++r) {
        unsigned long long gm = key[0];
#pragma unroll
        for (int s = 1; s < 16; ++s) gm = key[s] < gm ? key[s] : gm;
#pragma unroll
        for (int st = 1; st < 64; st <<= 1) {
            unsigned long long o = shfl_xor_u64(gm, st);
            gm = o < gm ? o : gm;
        }
        if (lane == r) outj = (int)(gm & 0xffffffffu);
#pragma unroll
        for (int s = 0; s < 16; ++s)
            if (key[s] == gm) key[s] = ~0ull;
    }
    if (lane < 16) idx[qorig * KNN + lane] = outj;
}

__device__ __forceinline__ int cellof(float x) {
    int c = (int)floorf((x - GLO) * INVH);
    return min(max(c, 0), GRID - 1);
}

// pos (N,3) -> pos4/pm2; cell id + histogram
__global__ void prep_kernel(const float* __restrict__ pos, float4* __restrict__ pos4,
                            float4* __restrict__ pm2, int* __restrict__ cellid,
                            int* __restrict__ hist) {
    int i = blockIdx.x * 256 + threadIdx.x;
    if (i < NPTS) {
        float x = pos[3 * i], y = pos[3 * i + 1], z = pos[3 * i + 2];
        float sq = fmaf(x, x, fmaf(y, y, z * z));
        pos4[i] = make_float4(x, y, z, sq);
        pm2[i] = make_float4(-2.f * x, -2.f * y, -2.f * z, sq);
        int c = (cellof(z) * GRID + cellof(y)) * GRID + cellof(x);
        cellid[i] = c;
        atomicAdd(&hist[c], 1);
    }
}

// single-block Hillis-Steele scan of the 32768-cell histogram
__global__ __launch_bounds__(1024) void scan_kernel(const int* __restrict__ hist,
                                                    int* __restrict__ cellstart,
                                                    int* __restrict__ cursor) {
    __shared__ int s[1024];
    int t = threadIdx.x;
    int base = 0;
    for (int c = 0; c < GRID3; c += 1024) {
        int v = hist[c + t];
        s[t] = v;
        __syncthreads();
        for (int off = 1; off < 1024; off <<= 1) {
            int x = (t >= off) ? s[t - off] : 0;
            __syncthreads();
            s[t] += x;
            __syncthreads();
        }
        int excl = base + s[t] - v;
        cellstart[c + t] = excl;
        cursor[c + t] = excl;
        int tot = s[1023];
        __syncthreads();
        base += tot;
    }
    if (t == 0) cellstart[GRID3] = base;
}

// scatter points into cell-sorted order (sorted m2 copy + orig id)
__global__ void scatter_kernel(const float4* __restrict__ pos4, const float4* __restrict__ pm2,
                               const int* __restrict__ cellid, int* __restrict__ cursor,
                               float4* __restrict__ ssp4, float4* __restrict__ spm2,
                               int* __restrict__ sid) {
    int i = blockIdx.x * 256 + threadIdx.x;
    if (i < NPTS) {
        int dst = atomicAdd(&cursor[cellid[i]], 1);
        ssp4[dst] = pos4[i];
        spm2[dst] = pm2[i];
        sid[dst] = i;
    }
}

// HYBRID kNN: tau from 512-pt sorted window (dense, coalesced; subset bound:
// any S with non-empty streams gives tau >= d16). Then ONE filtered brute
// pass over the ORIGINAL pm2 (R14's proven dense scan), wave-private LDS
// push, 3-slot rank-select. Fallback (ntot>SCAP): two-pass brute.
__global__ __launch_bounds__(256) void knn_kernel(const float4* __restrict__ ssp4,
                                                  const float4* __restrict__ spm2,
                                                  const int* __restrict__ sid,
                                                  const float4* __restrict__ pm2,
                                                  int* __restrict__ idx) {
    __shared__ unsigned long long keys[16][SCAP];   // 24KB, wave-private slices
    __shared__ int knt[16];
    int tid = threadIdx.x;
    int lane = tid & 63;
    int w = tid >> 6;
    int li0 = w * 4;
    int sq0 = blockIdx.x * 16 + w * 4;
    float qx[4], qy[4], qz[4];
    int qorig[4];
#pragma unroll
    for (int i = 0; i < 4; ++i) {
        float4 t = ssp4[sq0 + i];       // wave-uniform scalar load
        qx[i] = t.x; qy[i] = t.y; qz[i] = t.z;
        qorig[i] = sid[sq0 + i];
    }
    if (lane < 4) knt[li0 + lane] = 0;   // wave-private; same-wave LDS order

    // ---- Phase A: tau from sorted 512-pt window (branchless, dense) ----
    float tq[4];
#pragma unroll
    for (int i = 0; i < 4; ++i) {
        int wstart = min(max(sq0 + i - TWIN / 2, 0), NPTS - TWIN);
        float mnl = INFINITY;
#pragma unroll 2
        for (int c = 0; c < TWIN; c += 64)
            mnl = fminf(mnl, distm2(qx[i], qy[i], qz[i], spm2[wstart + c + lane]));
        float m = mnl;                    // streams = lane mod 16, 32 pts each
        m = fminf(m, __shfl_xor(m, 16, 64));
        m = fminf(m, __shfl_xor(m, 32, 64));
        m = fmaxf(m, __shfl_xor(m, 1, 64));
        m = fmaxf(m, __shfl_xor(m, 2, 64));
        m = fmaxf(m, __shfl_xor(m, 4, 64));
        m = fmaxf(m, __shfl_xor(m, 8, 64));
        tq[i] = m;                        // always finite; d16 <= tq
    }

    // ---- Phase B: single filtered scan over ORIGINAL pm2 (2-deep prefetch) --
    {
        float4 c0 = pm2[lane],       c1 = pm2[64 + lane];
        float4 d0 = pm2[128 + lane], d1 = pm2[192 + lane];
        for (int cb = 0; cb < NPTS; cb += 128) {
            int j0 = cb + lane, j1 = cb + 64 + lane;
#pragma unroll
            for (int i = 0; i < 4; ++i) {
                float va = distm2(qx[i], qy[i], qz[i], c0);
                float vb = distm2(qx[i], qy[i], qz[i], c1);
                if (fminf(va, vb) <= tq[i]) {
                    if (va <= tq[i]) { int s = atomicAdd(&knt[li0 + i], 1); if (s < SCAP) keys[li0 + i][s] = dkey(va, j0); }
                    if (vb <= tq[i]) { int s = atomicAdd(&knt[li0 + i], 1); if (s < SCAP) keys[li0 + i][s] = dkey(vb, j1); }
                }
            }
            c0 = d0; c1 = d1;
            d0 = pm2[cb + 256 + lane];    // pad (+320) makes last iters safe
            d1 = pm2[cb + 320 + lane];
        }
    }

    // ---- Extraction: 3-slot rank-select; fallback = two-pass brute ----
#pragma unroll
    for (int e = 0; e < 4; ++e) {
        int ntot = knt[li0 + e];          // same-wave: visible, ordered
        if (ntot > SCAP) {
            wave_brute2p(qx[e], qy[e], qz[e], pm2, lane, qorig[e], idx);
            continue;
        }
        // tau >= d16 guarantees ntot >= 16
        unsigned long long k0 = (lane < ntot) ? keys[li0 + e][lane] : ~0ull;
        unsigned long long k1 = (lane + 64 < ntot) ? keys[li0 + e][lane + 64] : ~0ull;
        unsigned long long k2 = (lane + 128 < ntot) ? keys[li0 + e][lane + 128] : ~0ull;
        int r0 = 0, r1 = 0, r2 = 0;
        for (int t = 0; t < ntot; ++t) {
            unsigned long long k = keys[li0 + e][t];   // broadcast ds_read
            r0 += (int)(k < k0);
            r1 += (int)(k < k1);
            r2 += (int)(k < k2);
        }
        int ob = qorig[e] * KNN;
        if (lane < ntot && r0 < KNN) idx[ob + r0] = (int)(k0 & 0xffffffffu);
        if (lane + 64 < ntot && r1 < KNN) idx[ob + r1] = (int)(k1 & 0xffffffffu);
        if (lane + 128 < ntot && r2 < KNN) idx[ob + r2] = (int)(k2 & 0xffffffffu);
    }
}

// FUSED EdgeConv1 + ec2_pre (h1 never touches global) — unchanged.
__global__ __launch_bounds__(256) void ec12_kernel(const float4* __restrict__ pos4,
                                                   const int* __restrict__ idx,
                                                   const float* __restrict__ W1,
                                                   const float* __restrict__ b1,
                                                   const float* __restrict__ W2,
                                                   const float* __restrict__ b2,
                                                   float* __restrict__ C2,
                                                   float* __restrict__ Y2) {
    __shared__ float h1s[16][64];
    int t = threadIdx.x & 63;
    int w = threadIdx.x >> 6;
    int pb = blockIdx.x * 16 + w * 4;
    float w0 = W1[0 * HID + t], w1 = W1[1 * HID + t], w2 = W1[2 * HID + t];
    float v0 = W1[3 * HID + t], v1 = W1[4 * HID + t], v2 = W1[5 * HID + t];
    float bt1 = b1[t];
#pragma unroll
    for (int i = 0; i < 4; ++i) {
        int p = pb + i;
        float4 xi = pos4[p];
        float C = bt1 + xi.x * (w0 - v0) + xi.y * (w1 - v1) + xi.z * (w2 - v2);
        float m = -INFINITY;
#pragma unroll
        for (int k = 0; k < KNN; ++k) {
            int j = idx[p * KNN + k];
            float4 xj = pos4[j];
            m = fmaxf(m, fmaf(xj.x, v0, fmaf(xj.y, v1, xj.z * v2)));
        }
        h1s[w * 4 + i][t] = fmaxf(C + m, 0.f);
    }
    __syncthreads();
    float aa[4] = {0.f, 0.f, 0.f, 0.f};
    float ab[4] = {0.f, 0.f, 0.f, 0.f};
#pragma unroll 8
    for (int f = 0; f < 64; ++f) {
        float wa = W2[f * HID + t];
        float wb = W2[(64 + f) * HID + t];
#pragma unroll
        for (int i = 0; i < 4; ++i) {
            float h = h1s[w * 4 + i][f];
            aa[i] = fmaf(h, wa, aa[i]);
            ab[i] = fmaf(h, wb, ab[i]);
        }
    }
    float bt = b2[t];
#pragma unroll
    for (int i = 0; i < 4; ++i) {
        C2[(pb + i) * HID + t] = bt + aa[i] - ab[i];
        Y2[(pb + i) * HID + t] = ab[i];
    }
}

__global__ __launch_bounds__(256) void ec2_maxpool_kernel(const float* __restrict__ C2,
                                                          const float* __restrict__ Y2,
                                                          const int* __restrict__ idx,
                                                          float* __restrict__ gpartial) {
    int t = threadIdx.x & 63;
    int lp = threadIdx.x >> 6;
    int p = blockIdx.x * 4 + lp;
    float m = -INFINITY;
#pragma unroll
    for (int k = 0; k < KNN; ++k) {
        int j = idx[p * KNN + k];
        m = fmaxf(m, Y2[j * HID + t]);
    }
    float val = fmaxf(C2[p * HID + t] + m, 0.f);
    __shared__ float red[4][64];
    red[lp][t] = val;
    __syncthreads();
    if (lp == 0) {
        float g = fmaxf(fmaxf(red[0][t], red[1][t]), fmaxf(red[2][t], red[3][t]));
        gpartial[blockIdx.x * 64 + t] = g;
    }
}

__global__ __launch_bounds__(256) void greduce2_kernel(const float* __restrict__ gpartial,
                                                       float* __restrict__ gp2) {
    __shared__ float red[4][64];
    int f = threadIdx.x & 63;
    int w = threadIdx.x >> 6;
    int r0 = blockIdx.x * 16 + w * 4;
    float m = -INFINITY;
#pragma unroll
    for (int r = 0; r < 4; ++r) m = fmaxf(m, gpartial[(r0 + r) * 64 + f]);
    red[w][f] = m;
    __syncthreads();
    if (w == 0)
        gp2[blockIdx.x * 64 + f] =
            fmaxf(fmaxf(red[0][f], red[1][f]), fmaxf(red[2][f], red[3][f]));
}

__global__ __launch_bounds__(256) void tail2_kernel(const float* __restrict__ gp2,
                                                    const float* __restrict__ Wc,
                                                    const float* __restrict__ bc,
                                                    float* __restrict__ out) {
    __shared__ float red[4][64];
    __shared__ float g[64];
    int f = threadIdx.x & 63;
    int w = threadIdx.x >> 6;
    float m = -INFINITY;
    for (int i = w; i < 256; i += 4) m = fmaxf(m, gp2[i * 64 + f]);
    red[w][f] = m;
    __syncthreads();
    if (w == 0) g[f] = fmaxf(fmaxf(red[0][f], red[1][f]), fmaxf(red[2][f], red[3][f]));
    __syncthreads();
    if (threadIdx.x < NCLS) {
        float a = bc[threadIdx.x];
#pragma unroll
        for (int h = 0; h < HID; ++h) a = fmaf(g[h], Wc[h * NCLS + threadIdx.x], a);
        out[threadIdx.x] = a;
    }
}

extern "C" void kernel_launch(void* const* d_in, const int* in_sizes, int n_in,
                              void* d_out, int out_size, void* d_ws, size_t ws_size,
                              hipStream_t stream) {
    const float* pos = (const float*)d_in[0];
    // d_in[1] = batch (all zeros, num_segments=1) -> unused
    const float* W1 = (const float*)d_in[2];
    const float* b1 = (const float*)d_in[3];
    const float* W2 = (const float*)d_in[4];
    const float* b2 = (const float*)d_in[5];
    const float* Wc = (const float*)d_in[6];
    const float* bc = (const float*)d_in[7];
    float* out = (float*)d_out;

    char* ws = (char*)d_ws;
    size_t o = 0;
    auto alloc = [&](size_t bytes) { size_t r = o; o += (bytes + 255) & ~size_t(255); return r; };
    size_t fm = (size_t)NPTS * HID * 4;
    size_t o_pos4 = alloc((size_t)NPTS * 16);
    size_t o_pm2 = alloc((size_t)(NPTS + 320) * 16);   // +320 prefetch pad
    size_t o_ssp4 = alloc((size_t)NPTS * 16);
    size_t o_spm2 = alloc((size_t)NPTS * 16);
    size_t o_cellid = alloc((size_t)NPTS * 4);
    size_t o_sid = alloc((size_t)NPTS * 4);
    size_t o_hist = alloc((size_t)GRID3 * 4);
    size_t o_cstart = alloc((size_t)(GRID3 + 1) * 4);
    size_t o_cursor = alloc((size_t)GRID3 * 4);
    size_t o_idx = alloc((size_t)NPTS * KNN * 4);
    size_t o_C2 = alloc(fm);
    size_t o_Y2 = alloc(fm);
    size_t o_gp = alloc((size_t)(NPTS / 4) * HID * 4);
    size_t o_gp2 = alloc((size_t)256 * HID * 4);

    float4* pos4 = (float4*)(ws + o_pos4);
    float4* pm2 = (float4*)(ws + o_pm2);
    float4* ssp4 = (float4*)(ws + o_ssp4);
    float4* spm2 = (float4*)(ws + o_spm2);
    int* cellid = (int*)(ws + o_cellid);
    int* sid = (int*)(ws + o_sid);
    int* hist = (int*)(ws + o_hist);
    int* cstart = (int*)(ws + o_cstart);
    int* cursor = (int*)(ws + o_cursor);
    int* idx = (int*)(ws + o_idx);
    float* C2 = (float*)(ws + o_C2);
    float* Y2 = (float*)(ws + o_Y2);
    float* gp = (float*)(ws + o_gp);
    float* gp2 = (float*)(ws + o_gp2);

    hipMemsetAsync(hist, 0, (size_t)GRID3 * 4, stream);
    hipMemsetAsync(pm2 + NPTS, 0, 320 * sizeof(float4), stream);  // prefetch pad

    prep_kernel<<<NPTS / 256, 256, 0, stream>>>(pos, pos4, pm2, cellid, hist);
    scan_kernel<<<1, 1024, 0, stream>>>(hist, cstart, cursor);
    scatter_kernel<<<NPTS / 256, 256, 0, stream>>>(pos4, pm2, cellid, cursor, ssp4, spm2, sid);
    knn_kernel<<<NPTS / 16, 256, 0, stream>>>(ssp4, spm2, sid, pm2, idx);
    ec12_kernel<<<NPTS / 16, 256, 0, stream>>>(pos4, idx, W1, b1, W2, b2, C2, Y2);
    ec2_maxpool_kernel<<<NPTS / 4, 256, 0, stream>>>(C2, Y2, idx, gp);
    greduce2_kernel<<<256, 256, 0, stream>>>(gp, gp2);
    tail2_kernel<<<1, 256, 0, stream>>>(gp2, Wc, bc, out);
}